// Round 7
// baseline (57.488 us; speedup 1.0000x reference)
//
#include <hip/hip_runtime.h>
#include <hip/hip_bf16.h>

// TT/MPO matvec on MFMA (bf16 in / f32 accum), round 7.
//   S1: T1[(o1l,i3)][(i2,k1)] = c0m x v        (per o1, K=16 pad 32)
//   S2: T2[(o1l,o2)][(i3,k2)] = c1m x T1       (waves = M4 x N2 grid)
//   S3: out[b,o1,o2,o3]       = c2m x T2       (wave w<4 owns o1l=w)
// Round-6 lesson: dur invariant to resident blocks (1 vs 2/CU) and barriers ->
// per-CU serialized LDS pipe is the limiter; S2's B-frags were read identically
// by all 8 waves (8x redundancy, 1024 ds_read_b128/block).
// This round: S2 wave grid M4xN2 (B-reads halved to 512/block); c1 A-frags
// (nc-invariant!) hoisted out of the nc loop (L2 re-stream 512->256KB/block);
// fa2 loaded inside S3 to cap VGPR (~210 < 256 @ 2 waves/SIMD).

typedef short bf16x8 __attribute__((ext_vector_type(8)));
typedef float f32x4 __attribute__((ext_vector_type(4)));

#define WS_A1_OFF 0        // c1 frags: 16 o2 x 8 ks x 64 lanes x 16B = 131072 B
#define WS_A0_OFF 131072   // c0 frags: 16 o1 x 64 lanes x 16B       = 16384 B
#define WS_A2_OFF 147456   // c2 frags:  8 ks x 64 lanes x 16B       = 8192 B
#define WS_NEEDED 155648

__device__ __forceinline__ unsigned short f2bf(float f) {
    union { float f; unsigned int u; } x; x.f = f;
    unsigned int u = x.u;
    u += 0x7fffu + ((u >> 16) & 1u);   // RNE
    return (unsigned short)(u >> 16);
}

__device__ __forceinline__ unsigned int pk_bf16(float lo, float hi) {
    __hip_bfloat162 h = __float22bfloat162_rn(make_float2(lo, hi));  // RNE, x=lo -> [15:0]
    unsigned int r;
    __builtin_memcpy(&r, &h, 4);
    return r;
}

// ---------------- repack: c0/c1/c2 -> bf16 A-fragment layout in ws ----------------
// k-dim orderings: S2 kappa=(i2,k1): i2=k>>4, k1=k&15.  S3 kappa2=(i3,k2): i3=k>>4, k2=k&15.
__global__ void tt_repack(const float* __restrict__ c0,
                          const float* __restrict__ c1,
                          const float* __restrict__ c2,
                          unsigned short* __restrict__ ws) {
    int idx = blockIdx.x * 256 + threadIdx.x;
    if (idx < 8192) {                      // A1 (c1): frag (o2, ks, lane); A-row m = k2
        int o2 = idx >> 9, ks = (idx >> 6) & 7, l = idx & 63;
        int k2 = l & 15;
        unsigned short* dst = ws + ((size_t)(o2 * 8 + ks) * 64 + l) * 8;
        #pragma unroll
        for (int j = 0; j < 8; ++j) {
            int k = ks * 32 + ((l >> 4) * 8) + j;      // kappa = (i2,k1)
            dst[j] = f2bf(c1[(k & 15) * 4096 + o2 * 256 + (k >> 4) * 16 + k2]);
        }
    } else if (idx < 9216) {               // A0 (c0): frag (o1, lane); A-row m = k1; K=16 pad
        int t = idx - 8192;
        int o1 = t >> 6, l = t & 63;
        unsigned short* dst = ws + WS_A0_OFF / 2 + ((size_t)o1 * 64 + l) * 8;
        #pragma unroll
        for (int j = 0; j < 8; ++j) {
            int k = ((l >> 4) * 8) + j;                // i1 (or pad)
            float v = (l < 32) ? c0[o1 * 256 + k * 16 + (l & 15)] : 0.f;
            dst[j] = f2bf(v);
        }
    } else if (idx < 9728) {               // A2 (c2): frag (ks, lane); A-row m = o3
        int t = idx - 9216;
        int ks = t >> 6, l = t & 63;
        unsigned short* dst = ws + WS_A2_OFF / 2 + ((size_t)ks * 64 + l) * 8;
        #pragma unroll
        for (int j = 0; j < 8; ++j) {
            int k = ks * 32 + ((l >> 4) * 8) + j;      // kappa2 = (i3,k2)
            dst[j] = f2bf(c2[(k & 15) * 256 + (l & 15) * 16 + (k >> 4)]);
        }
    }
}

// ---------------- main kernel: 512 threads = 8 waves, 1 block/CU ----------------
template <bool PACKED>
__global__ __launch_bounds__(512, 2) void tt_main(
    const float* __restrict__ vg, const float* __restrict__ c0,
    const float* __restrict__ c1, const float* __restrict__ c2,
    const unsigned short* __restrict__ ws, float* __restrict__ outg)
{
    __shared__ unsigned short T1[16384];    // [n=(o1l,i3) 64][k=(i2,k1) 256], byte ^ ((n&7)<<4)
    __shared__ unsigned short T2[2][16384]; // ping-pong per nc; [n=(o1l,o2)][k=(i3,k2)], same swz

    const int b   = blockIdx.x;
    const int t   = threadIdx.x;
    const int w   = t >> 6;        // wave 0..7
    const int l   = t & 63;
    const int l15 = l & 15;
    const int lg  = l >> 4;
    const int mg  = w >> 1;        // S2 M-group: o2 = 4*mg .. 4*mg+3
    const int ng  = w & 1;         // S2 N-group: o1l = 2*ng, 2*ng+1

    // ---- preload: v B-frags (this wave's 2 i2 values) ----
    bf16x8 fb0[2];
    {
        const float* vb = vg + (size_t)b * 4096;
        #pragma unroll
        for (int nt = 0; nt < 2; ++nt) {
            bf16x8 f = {0, 0, 0, 0, 0, 0, 0, 0};
            if (l < 32) {
                int i2 = 2 * w + nt;
                const float* p = vb + (lg * 8) * 256 + i2 * 16 + l15;
                #pragma unroll
                for (int j = 0; j < 8; ++j) f[j] = (short)f2bf(p[j * 256]);
            }
            fb0[nt] = f;
        }
    }

    // ---- hold c1 A-frags for the whole kernel (nc-invariant; 32 frags = 128 VGPR) ----
    bf16x8 fa1p[32];   // [rt*8+ks] for o2 = 4*mg+rt
    if constexpr (PACKED) {
        const unsigned short* a1p = ws + (size_t)l * 8;
        #pragma unroll
        for (int rt = 0; rt < 4; ++rt)
            #pragma unroll
            for (int ks = 0; ks < 8; ++ks)
                fa1p[rt * 8 + ks] = *(const bf16x8*)(a1p + ((size_t)((4 * mg + rt) * 8 + ks)) * 512);
    } else {
        for (int rt = 0; rt < 4; ++rt)
            for (int ks = 0; ks < 8; ++ks) {
                int o2 = 4 * mg + rt;
                bf16x8 f;
                for (int j = 0; j < 8; ++j) {
                    int k = ks * 32 + lg * 8 + j;
                    f[j] = (short)f2bf(c1[(k & 15) * 4096 + o2 * 256 + (k >> 4) * 16 + l15]);
                }
                fa1p[rt * 8 + ks] = f;
            }
    }

    for (int nc = 0; nc < 4; ++nc) {       // o1 chunk: o1 = nc*4 .. nc*4+3
        unsigned short* T2c = T2[nc & 1];

        // ---- prefetch this nc's c0 frags (latency hides under S1's first MFMAs) ----
        bf16x8 fa0p[4];
        if constexpr (PACKED) {
            #pragma unroll
            for (int mtl = 0; mtl < 4; ++mtl)
                fa0p[mtl] = *(const bf16x8*)(ws + WS_A0_OFF / 2 +
                                             ((size_t)(nc * 4 + mtl) * 64 + l) * 8);
        } else {
            for (int mtl = 0; mtl < 4; ++mtl) {
                bf16x8 f = {0, 0, 0, 0, 0, 0, 0, 0};
                if (l < 32) {
                    for (int j = 0; j < 8; ++j)
                        f[j] = (short)f2bf(c0[(nc * 4 + mtl) * 256 + (lg * 8 + j) * 16 + l15]);
                }
                fa0p[mtl] = f;
            }
        }

        // ---------- S1: T1 rows (o1l,i3), k=(i2,k1); wave covers i2 = 2w,2w+1 ----------
        #pragma unroll
        for (int mtl = 0; mtl < 4; ++mtl) {
            #pragma unroll
            for (int nt = 0; nt < 2; ++nt) {
                f32x4 z = {0.f, 0.f, 0.f, 0.f};
                f32x4 d = __builtin_amdgcn_mfma_f32_16x16x32_bf16(fa0p[mtl], fb0[nt], z, 0, 0, 0);
                // D: row=k1=lg*4+r, col=i3=l15; this tile: i2 = 2w+nt
                const int i2 = 2 * w + nt;
                const int n  = mtl * 16 + l15;
                int byte = (n * 512 + (i2 * 16 + lg * 4) * 2) ^ ((l15 & 7) << 4);
                uint2 wv;
                wv.x = pk_bf16(d[0], d[1]);
                wv.y = pk_bf16(d[2], d[3]);
                *(uint2*)((char*)T1 + byte) = wv;   // 4 consecutive k1 -> one b64
            }
        }
        __syncthreads();   // bar1: T1 complete

        // ---------- S2: wave (mg,ng) owns o2 = 4mg..4mg+3, o1l = 2ng,2ng+1 ----------
        {
            f32x4 acc[4][2];
            #pragma unroll
            for (int rt = 0; rt < 4; ++rt)
                #pragma unroll
                for (int ntl = 0; ntl < 2; ++ntl) acc[rt][ntl] = (f32x4){0.f, 0.f, 0.f, 0.f};

            #pragma unroll
            for (int ks = 0; ks < 8; ++ks) {
                #pragma unroll
                for (int ntl = 0; ntl < 2; ++ntl) {
                    const int nt = 2 * ng + ntl;
                    int byte = ((nt * 16 + l15) * 512 + (ks * 32 + lg * 8) * 2) ^ ((l15 & 7) << 4);
                    bf16x8 fb = *(const bf16x8*)((char*)T1 + byte);
                    acc[0][ntl] = __builtin_amdgcn_mfma_f32_16x16x32_bf16(fa1p[0 * 8 + ks], fb, acc[0][ntl], 0, 0, 0);
                    acc[1][ntl] = __builtin_amdgcn_mfma_f32_16x16x32_bf16(fa1p[1 * 8 + ks], fb, acc[1][ntl], 0, 0, 0);
                    acc[2][ntl] = __builtin_amdgcn_mfma_f32_16x16x32_bf16(fa1p[2 * 8 + ks], fb, acc[2][ntl], 0, 0, 0);
                    acc[3][ntl] = __builtin_amdgcn_mfma_f32_16x16x32_bf16(fa1p[3 * 8 + ks], fb, acc[3][ntl], 0, 0, 0);
                }
            }
            // flush: D row=k2=lg*4+r, col=(o1l=nt, i3=l15); T2 k=(i3,k2) -> r consecutive
            #pragma unroll
            for (int rt = 0; rt < 4; ++rt) {
                const int o2 = 4 * mg + rt;
                #pragma unroll
                for (int ntl = 0; ntl < 2; ++ntl) {
                    const int nt = 2 * ng + ntl;
                    int byte = ((nt * 16 + o2) * 512 + (l15 * 16 + lg * 4) * 2) ^ ((o2 & 7) << 4);
                    uint2 wv;
                    wv.x = pk_bf16(acc[rt][ntl][0], acc[rt][ntl][1]);
                    wv.y = pk_bf16(acc[rt][ntl][2], acc[rt][ntl][3]);
                    *(uint2*)((char*)T2c + byte) = wv;
                }
            }
        }
        __syncthreads();   // bar2: T2c complete; also licenses next nc's T1 overwrite

        // ---------- S3: waves 0..3 own o1l = w; fa2 loaded here (VGPR relief) ----------
        if (w < 4) {
            bf16x8 fa2[8];
            if constexpr (PACKED) {
                #pragma unroll
                for (int ks = 0; ks < 8; ++ks)
                    fa2[ks] = *(const bf16x8*)(ws + WS_A2_OFF / 2 + ((size_t)ks * 64 + l) * 8);
            } else {
                for (int ks = 0; ks < 8; ++ks) {
                    bf16x8 f;
                    for (int j = 0; j < 8; ++j) {
                        int k = ks * 32 + lg * 8 + j;
                        f[j] = (short)f2bf(c2[(k & 15) * 256 + l15 * 16 + (k >> 4)]);
                    }
                    fa2[ks] = f;
                }
            }
            f32x4 a3a = {0.f, 0.f, 0.f, 0.f};
            f32x4 a3b = {0.f, 0.f, 0.f, 0.f};
            #pragma unroll
            for (int ks = 0; ks < 8; ks += 2) {
                int byte0 = ((w * 16 + l15) * 512 + ((ks + 0) * 32 + lg * 8) * 2) ^ ((l15 & 7) << 4);
                int byte1 = ((w * 16 + l15) * 512 + ((ks + 1) * 32 + lg * 8) * 2) ^ ((l15 & 7) << 4);
                bf16x8 fbA = *(const bf16x8*)((char*)T2c + byte0);  // n=o2=l15, k=(i3,k2)
                bf16x8 fbB = *(const bf16x8*)((char*)T2c + byte1);
                a3a = __builtin_amdgcn_mfma_f32_16x16x32_bf16(fa2[ks],     fbA, a3a, 0, 0, 0);
                a3b = __builtin_amdgcn_mfma_f32_16x16x32_bf16(fa2[ks + 1], fbB, a3b, 0, 0, 0);
            }
            f32x4 acc3 = a3a + a3b;
            // D: row=o3=lg*4+r, col=o2=l15
            float* ob = outg + (size_t)b * 4096;
            *(f32x4*)(ob + (nc * 4 + w) * 256 + l15 * 16 + lg * 4) = acc3;
        }
        // no barrier: T2 ping-pong covers reuse; T1 overwrite guarded by bar2
    }
}

extern "C" void kernel_launch(void* const* d_in, const int* in_sizes, int n_in,
                              void* d_out, int out_size, void* d_ws, size_t ws_size,
                              hipStream_t stream) {
    const float* vg  = (const float*)d_in[0];
    const float* c0g = (const float*)d_in[1];
    const float* c1g = (const float*)d_in[2];
    const float* c2g = (const float*)d_in[3];
    float* outg = (float*)d_out;

    const int B = in_sizes[0] / 4096;
    const bool packed = (ws_size >= (size_t)WS_NEEDED) && (d_ws != nullptr);

    if (packed) {
        tt_repack<<<dim3(38), dim3(256), 0, stream>>>(c0g, c1g, c2g, (unsigned short*)d_ws);
        tt_main<true><<<dim3(B), dim3(512), 0, stream>>>(
            vg, c0g, c1g, c2g, (const unsigned short*)d_ws, outg);
    } else {
        tt_main<false><<<dim3(B), dim3(512), 0, stream>>>(
            vg, c0g, c1g, c2g, nullptr, outg);
    }
}

// Round 8
// 54.175 us; speedup vs baseline: 1.0611x; 1.0611x over previous
//
#include <hip/hip_runtime.h>
#include <hip/hip_bf16.h>

// TT/MPO matvec, round 8: algebraic restructure.
//   Offline (repack2): W12[(o1,o2,k2),(i1,i2)] = sum_k1 c0[o1,i1,k1]*c1[k1,o2,i2,k2]  (f32 math, bf16 store)
//   Main (tt_main2, NB=4 b/block, 256 blocks = 1/CU, ONE sequential block per CU):
//     stage vS[(bl,i3)][(i1,i2)] in LDS once;
//     per o1 (16): T2[(bl,i3)][(o2,k2)] = W12[o1] x vS   (K=256, 64 MFMA/wave)
//                  + S3(prev o1) interleaved to hide W12 L2 latency; 1 barrier/o1.
// Rounds 5-7 lesson: occupancy/barrier/LDS-traffic knobs inside the old 4-nc
// 3-phase skeleton were ALL flat at ~55us -> the short dependent phases were
// structural. This kills stage S1, T1, bar1, and 3/4 of the sequential blocks.
// Fallback (ws < 2.1 MB): round-7 kernels verbatim (passed at 57.5us).

typedef short bf16x8 __attribute__((ext_vector_type(8)));
typedef float f32x4 __attribute__((ext_vector_type(4)));

// ---- old (fallback) ws layout ----
#define WS_A1_OFF 0
#define WS_A0_OFF 131072
#define WS_A2_OFF 147456
#define WS_NEEDED 155648
// ---- new ws layout ----
#define WS2_W12_OFF 0              // 256 mt x 8 ks x 64 lanes x 16B = 2097152 B
#define WS2_C2_OFF  2097152        // 8 ks x 64 lanes x 16B          = 8192 B
#define WS2_NEEDED  2105344

__device__ __forceinline__ unsigned short f2bf(float f) {
    union { float f; unsigned int u; } x; x.f = f;
    unsigned int u = x.u;
    u += 0x7fffu + ((u >> 16) & 1u);   // RNE
    return (unsigned short)(u >> 16);
}

__device__ __forceinline__ unsigned int pk_bf16(float lo, float hi) {
    __hip_bfloat162 h = __float22bfloat162_rn(make_float2(lo, hi));  // RNE, lo -> [15:0]
    unsigned int r;
    __builtin_memcpy(&r, &h, 4);
    return r;
}

// =================== NEW PATH ===================

// repack2: blocks 0..255 build W12 frags; block 256 builds c2 frags.
// A-frag convention (as rounds 2-7): lane l holds row m=l&15, elems j: k = ks*32+(l>>4)*8+j.
__global__ void tt_repack2(const float* __restrict__ c0,
                           const float* __restrict__ c1,
                           const float* __restrict__ c2,
                           unsigned short* __restrict__ ws) {
    if (blockIdx.x < 256) {
        int idx = blockIdx.x * 512 + threadIdx.x;   // (mt, ks, l)
        int mt = idx >> 9, ks = (idx >> 6) & 7, l = idx & 63;
        int o1 = mt >> 4, o2 = mt & 15;
        int k2 = l & 15, lg = l >> 4;
        int i1 = 2 * ks + (lg >> 1);               // fixed per thread
        int i2b = (lg & 1) * 8;
        float c0row[16];
        #pragma unroll
        for (int k1 = 0; k1 < 16; ++k1) c0row[k1] = c0[o1 * 256 + i1 * 16 + k1];
        unsigned short* dst = ws + ((size_t)(mt * 8 + ks) * 64 + l) * 8;
        #pragma unroll
        for (int j = 0; j < 8; ++j) {
            int i2 = i2b + j;
            float s = 0.f;
            #pragma unroll
            for (int k1 = 0; k1 < 16; ++k1)
                s += c0row[k1] * c1[k1 * 4096 + o2 * 256 + i2 * 16 + k2];
            dst[j] = f2bf(s);
        }
    } else {
        int t = threadIdx.x;                        // (ks, l); A-row m = o3
        int ks = t >> 6, l = t & 63;
        unsigned short* dst = ws + WS2_C2_OFF / 2 + ((size_t)ks * 64 + l) * 8;
        #pragma unroll
        for (int j = 0; j < 8; ++j) {
            int k = ks * 32 + ((l >> 4) * 8) + j;   // kappa2 = (i3,k2): i3=k>>4, k2=k&15
            dst[j] = f2bf(c2[(k & 15) * 256 + (l & 15) * 16 + (k >> 4)]);
        }
    }
}

// main2: 512 threads = 8 waves; NB=4 batch elems/block; LDS 96KB -> 1 block/CU.
__global__ __launch_bounds__(512, 2) void tt_main2(
    const float* __restrict__ vg, const unsigned short* __restrict__ ws,
    float* __restrict__ outg)
{
    __shared__ unsigned short vS[16384];     // [(bl,i3) 64][kappa=(i1,i2) 256], byte ^ ((i3&7)<<4)
    __shared__ unsigned short T2[2][16384];  // ping-pong; [(bl,i3) 64][(o2,k2) 256], same swz

    const int b0  = blockIdx.x * 4;
    const int t   = threadIdx.x;
    const int w   = t >> 6;        // wave 0..7
    const int l   = t & 63;
    const int l15 = l & 15;
    const int lg  = l >> 4;

    // ---- c2 A-frags (held all kernel; 32 VGPR) ----
    bf16x8 fa2[8];
    #pragma unroll
    for (int ks = 0; ks < 8; ++ks)
        fa2[ks] = *(const bf16x8*)(ws + WS2_C2_OFF / 2 + ((size_t)ks * 64 + l) * 8);

    // ---- stage vS: thread = (bl = t>>7, i3 = (t>>3)&15, i1h = t&7) covers kappa 32-run ----
    {
        const int bl  = t >> 7;
        const int i3  = (t >> 3) & 15;
        const int i1h = t & 7;
        const float* vb = vg + (size_t)(b0 + bl) * 4096;
        const int rowbyte = (bl * 16 + i3) * 512;
        const int swz = (i3 & 7) << 4;
        #pragma unroll
        for (int q = 0; q < 4; ++q) {              // i1 = 2*i1h + (q>>1), i2 block = (q&1)*8
            const int i1  = 2 * i1h + (q >> 1);
            const int i2b = (q & 1) * 8;
            unsigned int pk[4];
            #pragma unroll
            for (int p = 0; p < 4; ++p) {
                float lo = vb[i1 * 256 + (i2b + 2 * p)     * 16 + i3];
                float hi = vb[i1 * 256 + (i2b + 2 * p + 1) * 16 + i3];
                pk[p] = pk_bf16(lo, hi);
            }
            int byte = (rowbyte + (i1 * 16 + i2b) * 2) ^ swz;
            *(uint4*)((char*)vS + byte) = make_uint4(pk[0], pk[1], pk[2], pk[3]);
        }
    }
    __syncthreads();

    const int o2a = w, o2b = w + 8;   // wave's two M-tiles (o2 values)

    int curr = 0;
    for (int o1 = 0; o1 < 16; ++o1) {
        // ---- A-frag loads for this o1 (2 mt x 8 ks = 16 frags, 64 VGPR), from L2 ws ----
        bf16x8 fA0[8], fA1[8];
        #pragma unroll
        for (int ks = 0; ks < 8; ++ks) {
            fA0[ks] = *(const bf16x8*)(ws + ((size_t)((o1 * 16 + o2a) * 8 + ks) * 64 + l) * 8);
            fA1[ks] = *(const bf16x8*)(ws + ((size_t)((o1 * 16 + o2b) * 8 + ks) * 64 + l) * 8);
        }

        // ---- S3 of previous o1 (waves 0..3, bl=w) — hides the A-load latency ----
        if (o1 > 0 && w < 4) {
            const unsigned short* T2p = T2[curr ^ 1];
            f32x4 a3a = {0.f, 0.f, 0.f, 0.f};
            f32x4 a3b = {0.f, 0.f, 0.f, 0.f};
            #pragma unroll
            for (int ks3 = 0; ks3 < 8; ks3 += 2) {
                const int i3A = 2 * ks3 + (lg >> 1);
                const int i3B = i3A + 2;
                const int k2b = (lg & 1) * 8;
                int byteA = ((w * 16 + i3A) * 512 + (l15 * 16 + k2b) * 2) ^ ((i3A & 7) << 4);
                int byteB = ((w * 16 + i3B) * 512 + (l15 * 16 + k2b) * 2) ^ ((i3B & 7) << 4);
                bf16x8 fbA = *(const bf16x8*)((char*)T2p + byteA);  // n=o2=l15, k=(i3,k2)
                bf16x8 fbB = *(const bf16x8*)((char*)T2p + byteB);
                a3a = __builtin_amdgcn_mfma_f32_16x16x32_bf16(fa2[ks3],     fbA, a3a, 0, 0, 0);
                a3b = __builtin_amdgcn_mfma_f32_16x16x32_bf16(fa2[ks3 + 1], fbB, a3b, 0, 0, 0);
            }
            f32x4 acc3 = a3a + a3b;
            // D: row=o3=lg*4+r, col=o2=l15
            *(f32x4*)(outg + (size_t)(b0 + w) * 4096 + (o1 - 1) * 256 + l15 * 16 + lg * 4) = acc3;
        }

        // ---- S2': T2[curr] = W12[o1] x vS; wave w owns o2 = {w, w+8}, all 4 bl ----
        {
            f32x4 acc[2][4];
            #pragma unroll
            for (int mi = 0; mi < 2; ++mi)
                #pragma unroll
                for (int nt = 0; nt < 4; ++nt) acc[mi][nt] = (f32x4){0.f, 0.f, 0.f, 0.f};

            #pragma unroll
            for (int ks = 0; ks < 8; ++ks) {
                #pragma unroll
                for (int nt = 0; nt < 4; ++nt) {
                    int byte = ((nt * 16 + l15) * 512 + (ks * 32 + lg * 8) * 2) ^ ((l15 & 7) << 4);
                    bf16x8 fb = *(const bf16x8*)((char*)vS + byte);   // n=i3=l15, k=kappa
                    acc[0][nt] = __builtin_amdgcn_mfma_f32_16x16x32_bf16(fA0[ks], fb, acc[0][nt], 0, 0, 0);
                    acc[1][nt] = __builtin_amdgcn_mfma_f32_16x16x32_bf16(fA1[ks], fb, acc[1][nt], 0, 0, 0);
                }
            }
            // flush: D row=k2=lg*4+r (consecutive), col=i3=l15; T2 row=(bl=nt,i3), col=(o2,k2)
            unsigned short* T2c = T2[curr];
            #pragma unroll
            for (int mi = 0; mi < 2; ++mi) {
                const int o2 = mi ? o2b : o2a;
                #pragma unroll
                for (int nt = 0; nt < 4; ++nt) {
                    int byte = ((nt * 16 + l15) * 512 + (o2 * 16 + lg * 4) * 2) ^ ((l15 & 7) << 4);
                    uint2 wv;
                    wv.x = pk_bf16(acc[mi][nt][0], acc[mi][nt][1]);
                    wv.y = pk_bf16(acc[mi][nt][2], acc[mi][nt][3]);
                    *(uint2*)((char*)T2c + byte) = wv;
                }
            }
        }
        __syncthreads();   // T2[curr] ready; S3(o1-1) reads finished before this point
        curr ^= 1;
    }

    // ---- final S3 (o1 = 15) ----
    if (w < 4) {
        const unsigned short* T2p = T2[curr ^ 1];
        f32x4 a3a = {0.f, 0.f, 0.f, 0.f};
        f32x4 a3b = {0.f, 0.f, 0.f, 0.f};
        #pragma unroll
        for (int ks3 = 0; ks3 < 8; ks3 += 2) {
            const int i3A = 2 * ks3 + (lg >> 1);
            const int i3B = i3A + 2;
            const int k2b = (lg & 1) * 8;
            int byteA = ((w * 16 + i3A) * 512 + (l15 * 16 + k2b) * 2) ^ ((i3A & 7) << 4);
            int byteB = ((w * 16 + i3B) * 512 + (l15 * 16 + k2b) * 2) ^ ((i3B & 7) << 4);
            bf16x8 fbA = *(const bf16x8*)((char*)T2p + byteA);
            bf16x8 fbB = *(const bf16x8*)((char*)T2p + byteB);
            a3a = __builtin_amdgcn_mfma_f32_16x16x32_bf16(fa2[ks3],     fbA, a3a, 0, 0, 0);
            a3b = __builtin_amdgcn_mfma_f32_16x16x32_bf16(fa2[ks3 + 1], fbB, a3b, 0, 0, 0);
        }
        f32x4 acc3 = a3a + a3b;
        *(f32x4*)(outg + (size_t)(b0 + w) * 4096 + 15 * 256 + l15 * 16 + lg * 4) = acc3;
    }
}

// =================== FALLBACK (round-7, passed) ===================

__global__ void tt_repack(const float* __restrict__ c0,
                          const float* __restrict__ c1,
                          const float* __restrict__ c2,
                          unsigned short* __restrict__ ws) {
    int idx = blockIdx.x * 256 + threadIdx.x;
    if (idx < 8192) {
        int o2 = idx >> 9, ks = (idx >> 6) & 7, l = idx & 63;
        int k2 = l & 15;
        unsigned short* dst = ws + ((size_t)(o2 * 8 + ks) * 64 + l) * 8;
        #pragma unroll
        for (int j = 0; j < 8; ++j) {
            int k = ks * 32 + ((l >> 4) * 8) + j;
            dst[j] = f2bf(c1[(k & 15) * 4096 + o2 * 256 + (k >> 4) * 16 + k2]);
        }
    } else if (idx < 9216) {
        int t = idx - 8192;
        int o1 = t >> 6, l = t & 63;
        unsigned short* dst = ws + WS_A0_OFF / 2 + ((size_t)o1 * 64 + l) * 8;
        #pragma unroll
        for (int j = 0; j < 8; ++j) {
            int k = ((l >> 4) * 8) + j;
            float v = (l < 32) ? c0[o1 * 256 + k * 16 + (l & 15)] : 0.f;
            dst[j] = f2bf(v);
        }
    } else if (idx < 9728) {
        int t = idx - 9216;
        int ks = t >> 6, l = t & 63;
        unsigned short* dst = ws + WS_A2_OFF / 2 + ((size_t)ks * 64 + l) * 8;
        #pragma unroll
        for (int j = 0; j < 8; ++j) {
            int k = ks * 32 + ((l >> 4) * 8) + j;
            dst[j] = f2bf(c2[(k & 15) * 256 + (l & 15) * 16 + (k >> 4)]);
        }
    }
}

template <bool PACKED>
__global__ __launch_bounds__(512, 2) void tt_main(
    const float* __restrict__ vg, const float* __restrict__ c0,
    const float* __restrict__ c1, const float* __restrict__ c2,
    const unsigned short* __restrict__ ws, float* __restrict__ outg)
{
    __shared__ unsigned short T1[16384];
    __shared__ unsigned short T2[2][16384];

    const int b = blockIdx.x;
    const int t = threadIdx.x;
    const int w = t >> 6, l = t & 63, l15 = l & 15, lg = l >> 4;
    const int mg = w >> 1, ng = w & 1;

    bf16x8 fb0[2];
    {
        const float* vb = vg + (size_t)b * 4096;
        #pragma unroll
        for (int nt = 0; nt < 2; ++nt) {
            bf16x8 f = {0, 0, 0, 0, 0, 0, 0, 0};
            if (l < 32) {
                int i2 = 2 * w + nt;
                const float* p = vb + (lg * 8) * 256 + i2 * 16 + l15;
                #pragma unroll
                for (int j = 0; j < 8; ++j) f[j] = (short)f2bf(p[j * 256]);
            }
            fb0[nt] = f;
        }
    }
    bf16x8 fa1p[32];
    if constexpr (PACKED) {
        const unsigned short* a1p = ws + (size_t)l * 8;
        #pragma unroll
        for (int rt = 0; rt < 4; ++rt)
            #pragma unroll
            for (int ks = 0; ks < 8; ++ks)
                fa1p[rt * 8 + ks] = *(const bf16x8*)(a1p + ((size_t)((4 * mg + rt) * 8 + ks)) * 512);
    } else {
        for (int rt = 0; rt < 4; ++rt)
            for (int ks = 0; ks < 8; ++ks) {
                int o2 = 4 * mg + rt;
                bf16x8 f;
                for (int j = 0; j < 8; ++j) {
                    int k = ks * 32 + lg * 8 + j;
                    f[j] = (short)f2bf(c1[(k & 15) * 4096 + o2 * 256 + (k >> 4) * 16 + l15]);
                }
                fa1p[rt * 8 + ks] = f;
            }
    }

    for (int nc = 0; nc < 4; ++nc) {
        unsigned short* T2c = T2[nc & 1];
        bf16x8 fa0p[4];
        if constexpr (PACKED) {
            #pragma unroll
            for (int mtl = 0; mtl < 4; ++mtl)
                fa0p[mtl] = *(const bf16x8*)(ws + WS_A0_OFF / 2 +
                                             ((size_t)(nc * 4 + mtl) * 64 + l) * 8);
        } else {
            for (int mtl = 0; mtl < 4; ++mtl) {
                bf16x8 f = {0, 0, 0, 0, 0, 0, 0, 0};
                if (l < 32) {
                    for (int j = 0; j < 8; ++j)
                        f[j] = (short)f2bf(c0[(nc * 4 + mtl) * 256 + (lg * 8 + j) * 16 + l15]);
                }
                fa0p[mtl] = f;
            }
        }
        #pragma unroll
        for (int mtl = 0; mtl < 4; ++mtl) {
            #pragma unroll
            for (int nt = 0; nt < 2; ++nt) {
                f32x4 z = {0.f, 0.f, 0.f, 0.f};
                f32x4 d = __builtin_amdgcn_mfma_f32_16x16x32_bf16(fa0p[mtl], fb0[nt], z, 0, 0, 0);
                const int i2 = 2 * w + nt;
                const int n  = mtl * 16 + l15;
                int byte = (n * 512 + (i2 * 16 + lg * 4) * 2) ^ ((l15 & 7) << 4);
                uint2 wv;
                wv.x = pk_bf16(d[0], d[1]);
                wv.y = pk_bf16(d[2], d[3]);
                *(uint2*)((char*)T1 + byte) = wv;
            }
        }
        __syncthreads();
        {
            f32x4 acc[4][2];
            #pragma unroll
            for (int rt = 0; rt < 4; ++rt)
                #pragma unroll
                for (int ntl = 0; ntl < 2; ++ntl) acc[rt][ntl] = (f32x4){0.f, 0.f, 0.f, 0.f};
            #pragma unroll
            for (int ks = 0; ks < 8; ++ks) {
                #pragma unroll
                for (int ntl = 0; ntl < 2; ++ntl) {
                    const int nt = 2 * ng + ntl;
                    int byte = ((nt * 16 + l15) * 512 + (ks * 32 + lg * 8) * 2) ^ ((l15 & 7) << 4);
                    bf16x8 fb = *(const bf16x8*)((char*)T1 + byte);
                    acc[0][ntl] = __builtin_amdgcn_mfma_f32_16x16x32_bf16(fa1p[0 * 8 + ks], fb, acc[0][ntl], 0, 0, 0);
                    acc[1][ntl] = __builtin_amdgcn_mfma_f32_16x16x32_bf16(fa1p[1 * 8 + ks], fb, acc[1][ntl], 0, 0, 0);
                    acc[2][ntl] = __builtin_amdgcn_mfma_f32_16x16x32_bf16(fa1p[2 * 8 + ks], fb, acc[2][ntl], 0, 0, 0);
                    acc[3][ntl] = __builtin_amdgcn_mfma_f32_16x16x32_bf16(fa1p[3 * 8 + ks], fb, acc[3][ntl], 0, 0, 0);
                }
            }
            #pragma unroll
            for (int rt = 0; rt < 4; ++rt) {
                const int o2 = 4 * mg + rt;
                #pragma unroll
                for (int ntl = 0; ntl < 2; ++ntl) {
                    const int nt = 2 * ng + ntl;
                    int byte = ((nt * 16 + o2) * 512 + (l15 * 16 + lg * 4) * 2) ^ ((o2 & 7) << 4);
                    uint2 wv;
                    wv.x = pk_bf16(acc[rt][ntl][0], acc[rt][ntl][1]);
                    wv.y = pk_bf16(acc[rt][ntl][2], acc[rt][ntl][3]);
                    *(uint2*)((char*)T2c + byte) = wv;
                }
            }
        }
        __syncthreads();
        if (w < 4) {
            bf16x8 fa2[8];
            if constexpr (PACKED) {
                #pragma unroll
                for (int ks = 0; ks < 8; ++ks)
                    fa2[ks] = *(const bf16x8*)(ws + WS_A2_OFF / 2 + ((size_t)ks * 64 + l) * 8);
            } else {
                for (int ks = 0; ks < 8; ++ks) {
                    bf16x8 f;
                    for (int j = 0; j < 8; ++j) {
                        int k = ks * 32 + lg * 8 + j;
                        f[j] = (short)f2bf(c2[(k & 15) * 256 + l15 * 16 + (k >> 4)]);
                    }
                    fa2[ks] = f;
                }
            }
            f32x4 a3a = {0.f, 0.f, 0.f, 0.f};
            f32x4 a3b = {0.f, 0.f, 0.f, 0.f};
            #pragma unroll
            for (int ks = 0; ks < 8; ks += 2) {
                int byte0 = ((w * 16 + l15) * 512 + ((ks + 0) * 32 + lg * 8) * 2) ^ ((l15 & 7) << 4);
                int byte1 = ((w * 16 + l15) * 512 + ((ks + 1) * 32 + lg * 8) * 2) ^ ((l15 & 7) << 4);
                bf16x8 fbA = *(const bf16x8*)((char*)T2c + byte0);
                bf16x8 fbB = *(const bf16x8*)((char*)T2c + byte1);
                a3a = __builtin_amdgcn_mfma_f32_16x16x32_bf16(fa2[ks],     fbA, a3a, 0, 0, 0);
                a3b = __builtin_amdgcn_mfma_f32_16x16x32_bf16(fa2[ks + 1], fbB, a3b, 0, 0, 0);
            }
            f32x4 acc3 = a3a + a3b;
            float* ob = outg + (size_t)b * 4096;
            *(f32x4*)(ob + (nc * 4 + w) * 256 + l15 * 16 + lg * 4) = acc3;
        }
    }
}

extern "C" void kernel_launch(void* const* d_in, const int* in_sizes, int n_in,
                              void* d_out, int out_size, void* d_ws, size_t ws_size,
                              hipStream_t stream) {
    const float* vg  = (const float*)d_in[0];
    const float* c0g = (const float*)d_in[1];
    const float* c1g = (const float*)d_in[2];
    const float* c2g = (const float*)d_in[3];
    float* outg = (float*)d_out;

    const int B = in_sizes[0] / 4096;

    if (ws_size >= (size_t)WS2_NEEDED && d_ws != nullptr && (B % 4) == 0) {
        tt_repack2<<<dim3(257), dim3(512), 0, stream>>>(
            c0g, c1g, c2g, (unsigned short*)d_ws);
        tt_main2<<<dim3(B / 4), dim3(512), 0, stream>>>(
            vg, (const unsigned short*)d_ws, outg);
    } else if (ws_size >= (size_t)WS_NEEDED && d_ws != nullptr) {
        tt_repack<<<dim3(38), dim3(256), 0, stream>>>(c0g, c1g, c2g, (unsigned short*)d_ws);
        tt_main<true><<<dim3(B), dim3(512), 0, stream>>>(
            vg, c0g, c1g, c2g, (const unsigned short*)d_ws, outg);
    } else {
        tt_main<false><<<dim3(B), dim3(512), 0, stream>>>(
            vg, c0g, c1g, c2g, nullptr, outg);
    }
}